// Round 12
// baseline (433.234 us; speedup 1.0000x reference)
//
#include <hip/hip_runtime.h>

// ---------- types ----------
typedef unsigned short u16;
typedef unsigned int   u32;
typedef __attribute__((ext_vector_type(4))) float f32x4;
typedef __attribute__((ext_vector_type(8))) __bf16 bf16x8;
typedef __attribute__((ext_vector_type(2))) u32  u32x2;
typedef __attribute__((ext_vector_type(4))) u32  u32x4;

#define LDS_CAST(p) ((__attribute__((address_space(3))) void*)(p))
#define GLB_CAST(p) ((const __attribute__((address_space(1))) void*)(p))

__device__ __forceinline__ void load_lds16(const void* g, void* l) {
    __builtin_amdgcn_global_load_lds(GLB_CAST(g), LDS_CAST(l), 16, 0, 0);
}

__device__ __forceinline__ u32 lds_off(const void* p) {
    return (u32)(size_t)(const __attribute__((address_space(3))) void*)p;
}

__device__ __forceinline__ u16 f2bf(float f) {
    union { float f; u32 u; } v; v.f = f;
    u32 r = (v.u + 0x7FFFu + ((v.u >> 16) & 1u)) >> 16;
    return (u16)r;
}

__device__ __forceinline__ u16 bfc(float f) {          // compiler bf16 cast
    return __builtin_bit_cast(u16, (__bf16)f);
}

__device__ __forceinline__ float exp2fast(float x) {
#if __has_builtin(__builtin_amdgcn_exp2f)
    return __builtin_amdgcn_exp2f(x);
#else
    return __expf(x * 0.6931471805599453f);
#endif
}

// ---------- kernel 1: RoPE + cast ----------
__global__ __launch_bounds__(256) void rope_cast(const float* __restrict__ x,
                                                 u16* __restrict__ xb,
                                                 u16* __restrict__ rxb) {
    int idx = blockIdx.x * 256 + threadIdx.x;      // one pair, total 4194304
    int e2 = (idx & 511) * 2;
    int t  = (idx >> 9) & 2047;
    float2 v = *(const float2*)&x[(size_t)idx * 2];
    float theta = expf(-0.0089944730194981f * (float)e2);
    float angle = (float)t * theta;
    float sa, ca;
    sincosf(angle, &sa, &ca);
    float r0 = v.x * ca - v.y * sa;
    float r1 = v.y * ca + v.x * sa;
    u32 xp  = (u32)f2bf(v.x) | ((u32)f2bf(v.y) << 16);
    u32 rxp = (u32)f2bf(r0)  | ((u32)f2bf(r1)  << 16);
    *(u32*)&xb[(size_t)idx * 2]  = xp;
    *(u32*)&rxb[(size_t)idx * 2] = rxp;
}

// ---------- kernel 2: weight cast ----------
__global__ __launch_bounds__(256) void wcast(const float* __restrict__ a,
                                             const float* __restrict__ b,
                                             const float* __restrict__ c,
                                             const float* __restrict__ d,
                                             u16* __restrict__ out) {
    int i = blockIdx.x * 256 + threadIdx.x;        // 4M total
    int w = i >> 20, j = i & 1048575;
    float v = (w == 0) ? a[j] : (w == 1) ? b[j] : (w == 2) ? c[j] : d[j];
    out[i] = f2bf(v);
}

// ---------- kernel 3: GEMM  C = A @ W^T ----------
// MODE 0: merged QKV. W rows 0..3071 = [Wq;Wk;Wv]; A = (n0<2048)? rx : x.
// MODE 1: O-projection, fp32 out + bias.
template <int MODE>
__global__ __launch_bounds__(256) void gemm128(const u16* __restrict__ A0,
                                               const u16* __restrict__ A1,
                                               const u16* __restrict__ W,
                                               u16* __restrict__ outb,
                                               float* __restrict__ outf,
                                               const float* __restrict__ bias) {
    constexpr int Kd = 1024;
    __shared__ u16 As[128 * 64];
    __shared__ u16 Bs[128 * 64];
    const int tid = threadIdx.x;
    const int m0 = blockIdx.x * 128;
    const int n0 = blockIdx.y * 128;
    const u16* A = (MODE == 0 && n0 >= 2048) ? A1 : A0;
    const int wid = tid >> 6, lane = tid & 63;
    const int wr = wid >> 1, wc = wid & 1;
    const int lr = lane & 15, lhi = lane >> 4;

    f32x4 acc[4][4] = {};

    for (int k0 = 0; k0 < Kd; k0 += 64) {
        if (k0) __syncthreads();
#pragma unroll
        for (int i = 0; i < 4; ++i) {
            int cidx = tid + 256 * i;
            int row = cidx >> 3, col = (cidx & 7) * 8;
            load_lds16(A + (size_t)(m0 + row) * Kd + k0 + col, &As[row * 64 + col]);
        }
#pragma unroll
        for (int i = 0; i < 4; ++i) {
            int cidx = tid + 256 * i;
            int row = cidx >> 3, col = (cidx & 7) * 8;
            load_lds16(W + (size_t)(n0 + row) * Kd + k0 + col, &Bs[row * 64 + col]);
        }
        __syncthreads();
#pragma unroll
        for (int c = 0; c < 2; ++c) {
            bf16x8 a[4], b[4];
#pragma unroll
            for (int m = 0; m < 4; ++m)
                a[m] = *(const bf16x8*)&As[(wr * 64 + m * 16 + lr) * 64 + c * 32 + lhi * 8];
#pragma unroll
            for (int n = 0; n < 4; ++n)
                b[n] = *(const bf16x8*)&Bs[(wc * 64 + n * 16 + lr) * 64 + c * 32 + lhi * 8];
#pragma unroll
            for (int m = 0; m < 4; ++m)
#pragma unroll
                for (int n = 0; n < 4; ++n)
                    acc[m][n] = __builtin_amdgcn_mfma_f32_16x16x32_bf16(a[m], b[n], acc[m][n], 0, 0, 0);
        }
    }

#pragma unroll
    for (int m = 0; m < 4; ++m) {
        int rowb = m0 + wr * 64 + m * 16 + lhi * 4;
#pragma unroll
        for (int n = 0; n < 4; ++n) {
            int col = n0 + wc * 64 + n * 16 + lr;
#pragma unroll
            for (int r = 0; r < 4; ++r) {
                int mg = rowb + r;
                float v = acc[m][n][r];
                if (MODE == 0) {
                    int bb = mg >> 11, t = mg & 2047;
                    int hg = col >> 6, d = col & 63;   // hg 0..47
                    outb[(size_t)(hg >> 4) * 8388608 +
                         (((size_t)(bb * 16 + (hg & 15)) * 2048) + t) * 64 + d] = bfc(v);
                } else {
                    outf[(size_t)mg * 1024 + col] = v + bias[col];
                }
            }
        }
    }
}

// ---------- attention dual-frag pass: 2x 16-row q-frags vs one 64-kv tile ----------
// exp2-domain softmax, defer-max (T13), swizzled P (v3 form), V tr-reads shared
// across both frags. Frag f active iff kv0 <= R_f+15; mask iff kv0+63 > R_f.
__device__ __forceinline__ void attn_pass2(const bf16x8 (&qa)[2][2],
                                           f32x4 (&acc)[2][4],
                                           float (&m_i)[2][4], float (&l_i)[2][4],
                                           const u16* ks, const u16* vcur, u32 vsb,
                                           u16* pw0, u16* pw1,
                                           int lr, int lhi, int kv0,
                                           int R0, int R1, bool use_tr) {
    const bool act[2] = { kv0 <= R0 + 15, kv0 <= R1 + 15 };
    const int  Rf[2]  = { R0, R1 };

    // ---- QK^T: kb shared by both frags ----
    f32x4 s[2][4] = {};
    __builtin_amdgcn_s_setprio(1);
#pragma unroll
    for (int c = 0; c < 2; ++c)
#pragma unroll
        for (int n = 0; n < 4; ++n) {
            int r = n * 16 + lr;
            bf16x8 kb = *(const bf16x8*)&ks[r * 64 + ((c * 32 + lhi * 8) ^ ((r & 7) * 8))];
            if (act[0]) s[0][n] = __builtin_amdgcn_mfma_f32_16x16x32_bf16(qa[0][c], kb, s[0][n], 0, 0, 0);
            if (act[1]) s[1][n] = __builtin_amdgcn_mfma_f32_16x16x32_bf16(qa[1][c], kb, s[1][n], 0, 0, 0);
        }
    __builtin_amdgcn_s_setprio(0);

    // ---- mask + online softmax per frag (independent chains -> ILP) ----
#pragma unroll
    for (int f = 0; f < 2; ++f) {
        if (!act[f]) continue;
        if (kv0 + 63 > Rf[f]) {                 // mask needed unless tile fully visible
#pragma unroll
            for (int n = 0; n < 4; ++n) {
                int kvg = kv0 + n * 16 + lr;
#pragma unroll
                for (int r = 0; r < 4; ++r)
                    if (kvg > Rf[f] + lhi * 4 + r) s[f][n][r] = -1e30f;
            }
        }
        float mx[4] = { -1e30f, -1e30f, -1e30f, -1e30f };
#pragma unroll
        for (int n = 0; n < 4; ++n)
#pragma unroll
            for (int r = 0; r < 4; ++r) mx[r] = fmaxf(mx[r], s[f][n][r]);
#pragma unroll
        for (int off = 8; off; off >>= 1)
#pragma unroll
            for (int r = 0; r < 4; ++r) mx[r] = fmaxf(mx[r], __shfl_xor(mx[r], off));

        bool up = false;
#pragma unroll
        for (int r = 0; r < 4; ++r) up = up || (mx[r] > m_i[f][r] + 8.0f);
        if (__any((int)up)) {
#pragma unroll
            for (int r = 0; r < 4; ++r) {
                float mnew = fmaxf(m_i[f][r], mx[r]);
                float sc = exp2fast(m_i[f][r] - mnew);
                m_i[f][r] = mnew;
                l_i[f][r] *= sc;
#pragma unroll
                for (int nd = 0; nd < 4; ++nd) acc[f][nd][r] *= sc;
            }
        }
        u16* pwf = f ? pw1 : pw0;
        float rs[4] = { 0.f, 0.f, 0.f, 0.f };
#pragma unroll
        for (int n = 0; n < 4; ++n)
#pragma unroll
            for (int r = 0; r < 4; ++r) {
                float pv = exp2fast(s[f][n][r] - m_i[f][r]);
                rs[r] += pv;
                int qloc = lhi * 4 + r;
                pwf[qloc * 64 + ((n * 16 + lr) ^ ((qloc & 7) * 8))] = bfc(pv);
            }
#pragma unroll
        for (int off = 8; off; off >>= 1)
#pragma unroll
            for (int r = 0; r < 4; ++r) rs[r] += __shfl_xor(rs[r], off);
#pragma unroll
        for (int r = 0; r < 4; ++r) l_i[f][r] += rs[r];
    }

    // ---- P @ V: V fragments loaded once, shared by both frags ----
    union VB { bf16x8 v; u32 w[4]; u16 h[8]; };
    VB vb[2][4];                       // [c][nd]
    bf16x8 pa[2][2];                   // [frag][c]
#pragma unroll
    for (int f = 0; f < 2; ++f) {
        if (!act[f]) continue;
        const u16* pwf = f ? pw1 : pw0;
#pragma unroll
        for (int c = 0; c < 2; ++c)
            pa[f][c] = *(const bf16x8*)&pwf[lr * 64 + ((c * 32 + lhi * 8) ^ ((lr & 7) * 8))];
    }
    if (use_tr) {
        u32x2 lo[2][4], hi[2][4];
#pragma unroll
        for (int c = 0; c < 2; ++c)
#pragma unroll
            for (int nd = 0; nd < 4; ++nd) {
                u32 a = vsb + (u32)((c * 32 + lhi * 8 + nd) * 128 + lr * 2);
                asm volatile("ds_read_b64_tr_b16 %0, %2\n\t"
                             "ds_read_b64_tr_b16 %1, %2 offset:512"
                             : "=&v"(lo[c][nd]), "=&v"(hi[c][nd]) : "v"(a));
            }
        asm volatile("s_waitcnt lgkmcnt(0)" ::: "memory");
        __builtin_amdgcn_sched_barrier(0);
#pragma unroll
        for (int c = 0; c < 2; ++c)
#pragma unroll
            for (int nd = 0; nd < 4; ++nd) {
                vb[c][nd].w[0] = lo[c][nd].x; vb[c][nd].w[1] = lo[c][nd].y;
                vb[c][nd].w[2] = hi[c][nd].x; vb[c][nd].w[3] = hi[c][nd].y;
            }
    } else {
#pragma unroll
        for (int c = 0; c < 2; ++c)
#pragma unroll
            for (int nd = 0; nd < 4; ++nd)
#pragma unroll
                for (int i = 0; i < 8; ++i) {
                    int k = c * 32 + lhi * 8 + i;
                    vb[c][nd].h[i] = vcur[((k >> 2) << 8) + (nd << 6) + ((k & 3) << 4) + lr];
                }
    }
    __builtin_amdgcn_s_setprio(1);
#pragma unroll
    for (int f = 0; f < 2; ++f) {
        if (!act[f]) continue;
#pragma unroll
        for (int c = 0; c < 2; ++c)
#pragma unroll
            for (int nd = 0; nd < 4; ++nd)
                acc[f][nd] = __builtin_amdgcn_mfma_f32_16x16x32_bf16(pa[f][c], vb[c][nd].v, acc[f][nd], 0, 0, 0);
    }
    __builtin_amdgcn_s_setprio(0);
}

// ---------- kernel 4: causal flash attention (v6.1 — 128-row paired tiles, dual-frag) ----------
// 128-row q-tiles, pairs (qtA = bx, qtB = 15-bx): per-block frag-passes = 68
// -> uniform. Grid 8x64 = 512 blocks = 2/CU. Every iteration runs 2
// independent frags per pass; V fragments shared; K/V traffic halved.
__global__ __launch_bounds__(256) void attn128(const u16* __restrict__ Q,
                                               const u16* __restrict__ K,
                                               const u16* __restrict__ V,
                                               u16* __restrict__ O) {
    constexpr int T = 2048;
    __shared__ u16 Ks[2][64 * 64];
    __shared__ u16 Vs[2][64 * 64];
    __shared__ u16 Ps[4][2][16 * 64];      // per-wave, per-frag P (swizzled)
    const int tid = threadIdx.x, wid = tid >> 6, lane = tid & 63;
    const int lr = lane & 15, lhi = lane >> 4;
    const int bh = blockIdx.y;
    const int qt[2] = { (int)blockIdx.x, 15 - (int)blockIdx.x };   // A, B 128-row tiles
    const size_t base = (size_t)bh * T * 64;
    const u16* Qp = Q + base;
    const u16* Kp = K + base;
    const u16* Vp = V + base;

    // frag rows: R[p][f] = qt[p]*128 + f*64 + wid*16
    int R[2][2];
#pragma unroll
    for (int p = 0; p < 2; ++p)
#pragma unroll
        for (int f = 0; f < 2; ++f) R[p][f] = qt[p] * 128 + f * 64 + wid * 16;

    // Q fragments, pre-scaled by 0.125 * log2(e) (exp2-domain softmax)
    const float QS = 0.18033688011112042f;
    bf16x8 qa[2][2][2];                    // [pass][frag][c]
#pragma unroll
    for (int p = 0; p < 2; ++p)
#pragma unroll
        for (int f = 0; f < 2; ++f)
#pragma unroll
            for (int c = 0; c < 2; ++c) {
                bf16x8 t = *(const bf16x8*)&Qp[(size_t)(R[p][f] + lr) * 64 + c * 32 + lhi * 8];
                bf16x8 o;
#pragma unroll
                for (int i = 0; i < 8; ++i) o[i] = (__bf16)((float)t[i] * QS);
                qa[p][f][c] = o;
            }

    f32x4 acc[2][2][4] = {};
    float m_i[2][2][4], l_i[2][2][4];
#pragma unroll
    for (int p = 0; p < 2; ++p)
#pragma unroll
        for (int f = 0; f < 2; ++f)
#pragma unroll
            for (int r = 0; r < 4; ++r) { m_i[p][f][r] = -1e30f; l_i[p][f][r] = 0.f; }

    // ---- one-time tr_read self-check: fill Vs[0] with value=index ----
    {
        u16* vt = (u16*)&Vs[0][0];
#pragma unroll
        for (int j = 0; j < 16; ++j) vt[tid * 16 + j] = (u16)(tid * 16 + j);
    }
    __syncthreads();
    bool use_tr;
    {
        const u32 vsb0 = lds_off(&Vs[0][0]);
        bool ok = true;
#pragma unroll
        for (int t = 0; t < 2; ++t) {
            const int c = t ? 1 : 0, nd = t ? 3 : 0;
            u32 a = vsb0 + (u32)((c * 32 + lhi * 8 + nd) * 128 + lr * 2);
            u32x2 lo, hi;
            asm volatile("ds_read_b64_tr_b16 %0, %2\n\t"
                         "ds_read_b64_tr_b16 %1, %2 offset:512"
                         : "=&v"(lo), "=&v"(hi) : "v"(a));
            asm volatile("s_waitcnt lgkmcnt(0)" ::: "memory");
            __builtin_amdgcn_sched_barrier(0);
            union { u32 w[4]; u16 h[8]; } u;
            u.w[0] = lo.x; u.w[1] = lo.y; u.w[2] = hi.x; u.w[3] = hi.y;
#pragma unroll
            for (int i = 0; i < 8; ++i) {
                int k = c * 32 + lhi * 8 + i;
                int e = ((k >> 2) << 8) + (nd << 6) + ((k & 3) << 4) + lr;
                ok = ok && (u.h[i] == (u16)e);
            }
        }
        use_tr = (bool)__all((int)ok);
    }
    __syncthreads();

    // ---- stage helper ----
#define STAGE(bb, kv0s)                                                          \
    {                                                                            \
        _Pragma("unroll")                                                        \
        for (int i = 0; i < 2; ++i) {                                            \
            int q = tid + 256 * i;                                               \
            int krow = q >> 3;                                                   \
            int kcol = ((q & 7) ^ (krow & 7)) * 8;                               \
            load_lds16(Kp + (size_t)((kv0s) + krow) * 64 + kcol, &Ks[bb][q * 8]);\
            int vk = ((q >> 5) << 2) + ((q >> 1) & 3);                           \
            int vd = (((q >> 3) & 3) << 4) + ((q & 1) << 3);                     \
            load_lds16(Vp + (size_t)((kv0s) + vk) * 64 + vd, &Vs[bb][q * 8]);    \
        }                                                                        \
    }

    STAGE(0, 0);
    __syncthreads();

    const int ntA = 2 * qt[0] + 2;         // kv tiles for pass A
    const int ntB = 2 * qt[1] + 2;         // kv tiles for pass B (loop bound)
    int buf = 0;
    for (int kt = 0; kt < ntB; ++kt) {
        const int kv0 = kt * 64;
        if (kt + 1 < ntB) STAGE(buf ^ 1, kv0 + 64);

        const u16* ks = Ks[buf];
        const u16* vcur = Vs[buf];
        const u32 vsb = lds_off(vcur);

        if (kt < ntA)
            attn_pass2(qa[0], acc[0], m_i[0], l_i[0], ks, vcur, vsb,
                       Ps[wid][0], Ps[wid][1], lr, lhi, kv0, R[0][0], R[0][1], use_tr);
        attn_pass2(qa[1], acc[1], m_i[1], l_i[1], ks, vcur, vsb,
                   Ps[wid][0], Ps[wid][1], lr, lhi, kv0, R[1][0], R[1][1], use_tr);

        __syncthreads();
        buf ^= 1;
    }
#undef STAGE

    // ---- epilogue: O[(b*T+q), h*64+d] for all 4 frags ----
    const int b = bh >> 4, h = bh & 15;
#pragma unroll
    for (int p = 0; p < 2; ++p)
#pragma unroll
        for (int f = 0; f < 2; ++f)
#pragma unroll
            for (int nd = 0; nd < 4; ++nd)
#pragma unroll
                for (int r = 0; r < 4; ++r) {
                    int d = h * 64 + nd * 16 + lr;
                    int qg = R[p][f] + lhi * 4 + r;
                    O[(size_t)(b * 2048 + qg) * 1024 + d] = bfc(acc[p][f][nd][r] / l_i[p][f][r]);
                }
}

// ---------- launch ----------
extern "C" void kernel_launch(void* const* d_in, const int* in_sizes, int n_in,
                              void* d_out, int out_size, void* d_ws, size_t ws_size,
                              hipStream_t stream) {
    const float* x  = (const float*)d_in[0];
    const float* Wq = (const float*)d_in[1];
    const float* Wk = (const float*)d_in[2];
    const float* Wv = (const float*)d_in[3];
    const float* Wo = (const float*)d_in[4];
    const float* bo = (const float*)d_in[5];

    char* ws = (char*)d_ws;
    u16* Wqb = (u16*)ws;              // [Wq;Wk;Wv;Wo] bf16, 4M elems contiguous
    u16* Wob = Wqb + 3 * (1 << 20);
    u16* xb  = (u16*)(ws + (size_t)8 * 1024 * 1024);
    u16* rxb = xb  + (size_t)8388608;
    u16* Qb  = rxb + (size_t)8388608;   // Q,K,V contiguous 8M-elem blocks
    u16* Kb  = Qb  + (size_t)8388608;
    u16* Vb  = Kb  + (size_t)8388608;
    u16* Ob  = Vb  + (size_t)8388608;

    rope_cast<<<16384, 256, 0, stream>>>(x, xb, rxb);
    wcast<<<16384, 256, 0, stream>>>(Wq, Wk, Wv, Wo, Wqb);

    gemm128<0><<<dim3(64, 24), 256, 0, stream>>>(rxb, xb, Wqb, Qb, nullptr, nullptr);

    attn128<<<dim3(8, 64), 256, 0, stream>>>(Qb, Kb, Vb, Ob);

    gemm128<1><<<dim3(64, 8), 256, 0, stream>>>(Ob, Ob, Wob, nullptr, (float*)d_out, bo);
}